// Round 9
// baseline (56.285 us; speedup 1.0000x reference)
//
#include <hip/hip_runtime.h>

typedef __attribute__((ext_vector_type(8))) short bf16x8;
typedef __attribute__((ext_vector_type(4))) float f32x4;

namespace {
constexpr int NB=8, N1=4096, N2=1024, F1=128, F2=256, H2=256;
constexpr int TM=32;
constexpr float SLOPE=0.2f, EPSD=1e-10f;
constexpr size_t WS_CAND=0;                    // 32768 rows * 32 B = 1 MB
constexpr size_t WS_W1A=1048576;               // 128 frags * 1KB
constexpr size_t WS_W1B=1048576+131072;        // 64 frags
constexpr size_t WS_W2 =1048576+196608;        // 128 frags
constexpr size_t WS_Y2 =1048576+327680;        // 8*1024*256 f32 = 8 MB
constexpr int A_STRIDE=528;    // 256-k bf16 row: 512B + 16 pad
constexpr int P_STRIDE=272;    // 128-k bf16 row: 256B + 16 pad
constexpr int B_STRIDE=1040;   // 256-col f32 row: 1024B + 16 pad
}

__device__ __forceinline__ unsigned short f2bf(float f){
  union{float f; unsigned u;} v; v.f=f;
  unsigned r = v.u + 0x7FFFu + ((v.u>>16)&1u);   // RNE
  return (unsigned short)(r>>16);
}
__device__ __forceinline__ float lrelu(float x){ return x>=0.f? x : SLOPE*x; }

// ===== K0: W1A/W1B/W2 -> bf16 frag-linear (frag = s*16 + nq*4 + nt; lane 16B =
// 8 k-bf16 for n = nq*64+nt*16+(ln&15), k0 = s*32+(ln>>4)*8) =====
__global__ __launch_bounds__(256)
void k0_w(const float* __restrict__ W1, const float* __restrict__ W2,
          char* __restrict__ ws)
{
  int id = blockIdx.x*256 + threadIdx.x;
  const float* src; size_t dst;
  if (id < 8192) {                              // W1A: k rows 0..255
    int frag = id >> 6, ln = id & 63;
    int n = (((frag>>2)&3)*64) + ((frag&3)*16) + (ln & 15);
    int k0 = (frag>>4)*32 + (ln>>4)*8;
    src = W1 + (size_t)k0*256 + n;
    dst = WS_W1A + (size_t)frag*1024 + ln*16;
  } else if (id < 12288) {                      // W1B: k rows 256..383
    int fid = id - 8192, frag = fid >> 6, ln = fid & 63;
    int n = (((frag>>2)&3)*64) + ((frag&3)*16) + (ln & 15);
    int k0 = 256 + (frag>>4)*32 + (ln>>4)*8;
    src = W1 + (size_t)k0*256 + n;
    dst = WS_W1B + (size_t)frag*1024 + ln*16;
  } else if (id < 20480) {                      // W2
    int fid = id - 12288, frag = fid >> 6, ln = fid & 63;
    int n = (((frag>>2)&3)*64) + ((frag&3)*16) + (ln & 15);
    int k0 = (frag>>4)*32 + (ln>>4)*8;
    src = W2 + (size_t)k0*256 + n;
    dst = WS_W2 + (size_t)frag*1024 + ln*16;
  } else return;
  unsigned u[4];
  #pragma unroll
  for (int p=0;p<4;++p)
    u[p] = (unsigned)f2bf(src[(2*p)*256]) | ((unsigned)f2bf(src[(2*p+1)*256])<<16);
  *(uint4*)(ws + dst) = make_uint4(u[0],u[1],u[2],u[3]);
}

// ===== K1: blocks 0..1023 = 3-NN scan; 1024..1279 = Y2 = p2 @ W1A =====
__global__ __launch_bounds__(256, 2)
void k1_nn_y2(const float* __restrict__ xyz1, const float* __restrict__ xyz2,
              const float* __restrict__ p2, char* __restrict__ ws)
{
  __shared__ __align__(16) char smem[24576];
  const int t = threadIdx.x;
  const int blk = blockIdx.x;
  const int b = blk & 7;                        // batch == XCD (1024%8==0)
  const int lane = t & 63;

  if (blk >= 1024) {                            // ---- Y2 GEMM block ----
    const int jt = (blk - 1024) >> 3;
    const int j0 = jt * 32;
    const int wv = t >> 6, nq = wv;
    const int lrow = lane & 15, lg = lane >> 4;
    // A-tile: p2 rows j0..j0+31, 256 k -> bf16 LDS
    {
      const int rr = t >> 3, qq = t & 7;
      const float4* q = (const float4*)(p2 + ((size_t)b*N2 + j0 + rr)*F2 + qq*32);
      float4 a[8];
      #pragma unroll
      for (int p=0;p<8;++p) a[p] = q[p];
      #pragma unroll
      for (int p=0;p<4;++p) {
        unsigned u0 = (unsigned)f2bf(a[2*p].x)   | ((unsigned)f2bf(a[2*p].y)<<16);
        unsigned u1 = (unsigned)f2bf(a[2*p].z)   | ((unsigned)f2bf(a[2*p].w)<<16);
        unsigned u2 = (unsigned)f2bf(a[2*p+1].x) | ((unsigned)f2bf(a[2*p+1].y)<<16);
        unsigned u3 = (unsigned)f2bf(a[2*p+1].z) | ((unsigned)f2bf(a[2*p+1].w)<<16);
        *(uint4*)(smem + rr*A_STRIDE + (qq*4+p)*16) = make_uint4(u0,u1,u2,u3);
      }
    }
    const char* wA = ws + WS_W1A;
    auto loadW = [&](int s, bf16x8* dst){
      #pragma unroll
      for (int nt=0;nt<4;++nt)
        dst[nt] = *(const bf16x8*)(wA + ((s*16 + nq*4 + nt)<<10) + lane*16);
    };
    f32x4 acc[2][4];
    #pragma unroll
    for (int mt=0;mt<2;++mt)
      #pragma unroll
      for (int nt=0;nt<4;++nt) acc[mt][nt] = (f32x4){0.f,0.f,0.f,0.f};
    bf16x8 bwA[4], bwB[4];
    loadW(0, bwA); loadW(1, bwB);
    __syncthreads();
    auto gstep = [&](int s, const bf16x8* bw){
      bf16x8 af[2];
      #pragma unroll
      for (int mt=0;mt<2;++mt)
        af[mt] = *(const bf16x8*)(smem + (mt*16+lrow)*A_STRIDE + (s*4+lg)*16);
      #pragma unroll
      for (int mt=0;mt<2;++mt)
        #pragma unroll
        for (int nt=0;nt<4;++nt)
          acc[mt][nt] = __builtin_amdgcn_mfma_f32_16x16x32_bf16(af[mt], bw[nt], acc[mt][nt], 0,0,0);
    };
    #pragma unroll
    for (int u=0; u<4; ++u) {
      gstep(2*u, bwA);   if (u<3) loadW(2*u+2, bwA);
      gstep(2*u+1, bwB); if (u<3) loadW(2*u+3, bwB);
    }
    float* yb = (float*)(ws + WS_Y2) + ((size_t)b*N2 + j0)*256;
    #pragma unroll
    for (int mt=0;mt<2;++mt)
      #pragma unroll
      for (int rg=0;rg<4;++rg) {
        const int row = mt*16 + lg*4 + rg;
        #pragma unroll
        for (int nt=0;nt<4;++nt)
          yb[(size_t)row*256 + nq*64 + nt*16 + lrow] = acc[mt][nt][rg];
      }
    return;
  }

  // ---- 3-NN block (round-8 structure, verified) ----
  const int row0 = (blk >> 3) * TM;
  float4* xq = (float4*)smem;                   // 16 KB
  char* cand = smem + 16384;                    // 8 KB
  const float* xz = xyz2 + (size_t)b*N2*3;
  for (int j = t; j < N2; j += 256) {
    float x = xz[3*j], y = xz[3*j+1], z = xz[3*j+2];
    xq[j] = make_float4(x, y, z, x*x + y*y + z*z);
  }
  __syncthreads();
  {
    const int row = t & 31, slice = t >> 5;
    const float* x1 = xyz1 + ((size_t)b*N1 + row0 + row)*3;
    const float px=x1[0], py=x1[1], pz=x1[2];
    const float sq1 = px*px + py*py + pz*pz;
    float d0=3.4e38f, d1=3.4e38f, d2=3.4e38f;
    int i0=0, i1=0, i2=0;
    const int j0 = slice*128;
    #pragma unroll 8
    for (int j = j0; j < j0+128; ++j) {
      float4 q = xq[j];
      float dot = px*q.x + py*q.y + pz*q.z;
      float d = fmaf(-2.f, dot, sq1 + q.w);
      bool c0 = d < d0, c1 = d < d1, c2 = d < d2;
      i2 = c1 ? i1 : (c2 ? j : i2);
      i1 = c0 ? i0 : (c1 ? j : i1);
      i0 = c0 ? j  : i0;
      d2 = __builtin_amdgcn_fmed3f(d, d1, d2);
      d1 = __builtin_amdgcn_fmed3f(d, d0, d1);
      d0 = fminf(d, d0);
    }
    float* cd = (float*)(cand + (slice*32 + row)*32);
    cd[0]=d0; cd[1]=d1; cd[2]=d2;
    ((int*)cd)[4]=i0; ((int*)cd)[5]=i1; ((int*)cd)[6]=i2;
  }
  __syncthreads();
  if (t < TM) {                                 // merge 8 slices, j-ascending
    float d0=3.4e38f,d1=3.4e38f,d2=3.4e38f; int i0=0,i1=0,i2=0;
    for (int p=0;p<8;++p){
      const float* cd = (const float*)(cand + (p*32 + t)*32);
      for (int c=0;c<3;++c){
        float d = cd[c]; int ii = ((const int*)cd)[4+c];
        if (d < d2) {
          if (d < d1) { d2=d1; i2=i1;
            if (d < d0) { d1=d0; i1=i0; d0=d; i0=ii; } else { d1=d; i1=ii; }
          } else { d2=d; i2=ii; }
        }
      }
    }
    d0=fmaxf(d0,EPSD); d1=fmaxf(d1,EPSD); d2=fmaxf(d2,EPSD);
    float w0=1.f/d0, w1=1.f/d1, w2=1.f/d2, inv=1.f/(w0+w1+w2);
    float o[8];
    o[0]=w0*inv; o[1]=w1*inv; o[2]=w2*inv; o[3]=0.f;
    ((int*)o)[4]=i0; ((int*)o)[5]=i1; ((int*)o)[6]=i2; ((int*)o)[7]=0;
    float4* dst = (float4*)(ws + WS_CAND + ((size_t)b*N1 + row0 + t)*32);
    dst[0] = make_float4(o[0],o[1],o[2],o[3]);
    dst[1] = *(float4*)&o[4];
  }
}

// ===== K2: h = lrelu(p1@W1B + gathersum(Y2) + b1); out = lrelu(h@W2 + b2) =====
__global__ __launch_bounds__(256, 2)
void k2_mlp(const float* __restrict__ p1, const char* __restrict__ ws,
            const float* __restrict__ b1, const float* __restrict__ b2,
            float* __restrict__ out)
{
  __shared__ __align__(16) char smem[33536];    // A: h bf16 [0,16896); B: [16896,33536)
  __shared__ float s_w[TM][4];
  __shared__ int   s_idx[TM][4];
  char* A = smem;
  char* Bp = smem + 16896;                      // X tile (8704 B) then h_pre halves

  const int t = threadIdx.x;
  const int b = blockIdx.x & 7;
  const int row0 = (blockIdx.x >> 3) * TM;
  const int lane = t & 63, wv = t >> 6;
  const int lrow = lane & 15, lg = lane >> 4;
  const int nq = wv;

  // cand -> LDS
  {
    const unsigned* src = (const unsigned*)(ws + WS_CAND) + ((size_t)b*N1 + row0)*8;
    const int r = t >> 3, c = t & 7;
    unsigned v = src[t];
    if (c < 3)                 s_w[r][c]     = __uint_as_float(v);
    else if (c >= 4 && c < 7)  s_idx[r][c-4] = (int)v;
  }

  // X tile: p1 rows (no gather), 128 k bf16
  {
    const int rr = t >> 3, qq = t & 7;
    const float4* q = (const float4*)(p1 + ((size_t)b*N1 + row0 + rr)*F1 + qq*16);
    float4 a0 = q[0], a1 = q[1], a2 = q[2], a3 = q[3];
    unsigned u0 = (unsigned)f2bf(a0.x) | ((unsigned)f2bf(a0.y)<<16);
    unsigned u1 = (unsigned)f2bf(a0.z) | ((unsigned)f2bf(a0.w)<<16);
    unsigned u2 = (unsigned)f2bf(a1.x) | ((unsigned)f2bf(a1.y)<<16);
    unsigned u3 = (unsigned)f2bf(a1.z) | ((unsigned)f2bf(a1.w)<<16);
    *(uint4*)(Bp + rr*P_STRIDE + (qq*2)*16) = make_uint4(u0,u1,u2,u3);
    u0 = (unsigned)f2bf(a2.x) | ((unsigned)f2bf(a2.y)<<16);
    u1 = (unsigned)f2bf(a2.z) | ((unsigned)f2bf(a2.w)<<16);
    u2 = (unsigned)f2bf(a3.x) | ((unsigned)f2bf(a3.y)<<16);
    u3 = (unsigned)f2bf(a3.z) | ((unsigned)f2bf(a3.w)<<16);
    *(uint4*)(Bp + rr*P_STRIDE + (qq*2+1)*16) = make_uint4(u0,u1,u2,u3);
  }

  auto loadW = [&](size_t wsoff, int s, bf16x8* dst){
    const char* base = ws + wsoff;
    #pragma unroll
    for (int nt=0;nt<4;++nt)
      dst[nt] = *(const bf16x8*)(base + ((s*16 + nq*4 + nt)<<10) + lane*16);
  };
  bf16x8 bwA[4], bwB[4];
  loadW(WS_W1B, 0, bwA); loadW(WS_W1B, 1, bwB);

  float bb1[4], bb2[4];
  #pragma unroll
  for (int nt=0;nt<4;++nt) {
    bb1[nt] = b1[nq*64 + nt*16 + lrow];
    bb2[nt] = b2[nq*64 + nt*16 + lrow];
  }
  __syncthreads();

  // GEMM1b: p1(32x128) @ W1B, 4 K32 steps
  f32x4 acc[2][4];
  #pragma unroll
  for (int mt=0;mt<2;++mt)
    #pragma unroll
    for (int nt=0;nt<4;++nt) acc[mt][nt] = (f32x4){0.f,0.f,0.f,0.f};
  auto gstep = [&](int s, const bf16x8* bw, f32x4 (&ac)[2][4],
                   const char* Ab, int stride){
    bf16x8 af[2];
    #pragma unroll
    for (int mt=0;mt<2;++mt)
      af[mt] = *(const bf16x8*)(Ab + (mt*16+lrow)*stride + (s*4+lg)*16);
    #pragma unroll
    for (int mt=0;mt<2;++mt)
      #pragma unroll
      for (int nt=0;nt<4;++nt)
        ac[mt][nt] = __builtin_amdgcn_mfma_f32_16x16x32_bf16(af[mt], bw[nt], ac[mt][nt], 0,0,0);
  };
  gstep(0, bwA, acc, Bp, P_STRIDE); loadW(WS_W1B, 2, bwA);
  gstep(1, bwB, acc, Bp, P_STRIDE); loadW(WS_W1B, 3, bwB);
  gstep(2, bwA, acc, Bp, P_STRIDE); loadW(WS_W2, 0, bwA);
  gstep(3, bwB, acc, Bp, P_STRIDE); loadW(WS_W2, 1, bwB);
  __syncthreads();                              // X dead; Bp becomes h_pre

  // two halves: gather-sum rows hh*16..+16 into Bp (f32), fold into acc, emit h bf16
  const float* y2b = (const float*)(ws + WS_Y2) + (size_t)b*N2*256;
  #pragma unroll
  for (int hh=0; hh<2; ++hh) {
    {                                           // gather-sum 16 rows x 256 cols
      const int tr = t >> 4, tq = t & 15;
      const int row = hh*16 + tr;
      const float w0 = s_w[row][0], w1 = s_w[row][1], w2 = s_w[row][2];
      const float4* y0 = (const float4*)(y2b + (size_t)s_idx[row][0]*256 + tq*16);
      const float4* y1 = (const float4*)(y2b + (size_t)s_idx[row][1]*256 + tq*16);
      const float4* y2 = (const float4*)(y2b + (size_t)s_idx[row][2]*256 + tq*16);
      #pragma unroll
      for (int p=0;p<4;++p) {
        float4 a0 = y0[p], a1 = y1[p], a2 = y2[p];
        float4 v;
        v.x = fmaf(w2, a2.x, fmaf(w1, a1.x, w0*a0.x));
        v.y = fmaf(w2, a2.y, fmaf(w1, a1.y, w0*a0.y));
        v.z = fmaf(w2, a2.z, fmaf(w1, a1.z, w0*a0.z));
        v.w = fmaf(w2, a2.w, fmaf(w1, a1.w, w0*a0.w));
        *(float4*)(Bp + tr*B_STRIDE + tq*64 + p*16) = v;
      }
    }
    __syncthreads();
    {                                           // acc += h_pre + b1, lrelu -> h bf16
      #pragma unroll
      for (int rg=0;rg<4;++rg) {
        const int row = hh*16 + lg*4 + rg;
        #pragma unroll
        for (int nt=0;nt<4;++nt) {
          const int col = nq*64 + nt*16 + lrow;
          float hp = *(const float*)(Bp + (lg*4+rg)*B_STRIDE + col*4);
          float v = lrelu(acc[hh][nt][rg] + hp + bb1[nt]);
          *(short*)(A + row*A_STRIDE + col*2) = (short)f2bf(v);
        }
      }
    }
    __syncthreads();
  }

  // GEMM2: h(32x256) @ W2, 8 K32 steps, dist-2
  f32x4 acc2[2][4];
  #pragma unroll
  for (int mt=0;mt<2;++mt)
    #pragma unroll
    for (int nt=0;nt<4;++nt) acc2[mt][nt] = (f32x4){0.f,0.f,0.f,0.f};
  #pragma unroll
  for (int u=0; u<4; ++u) {
    gstep(2*u, bwA, acc2, A, A_STRIDE);   if (u<3) loadW(WS_W2, 2*u+2, bwA);
    gstep(2*u+1, bwB, acc2, A, A_STRIDE); if (u<3) loadW(WS_W2, 2*u+3, bwB);
  }

  // epilogue
  {
    float* ob = out + ((size_t)b*N1 + row0) * H2;
    #pragma unroll
    for (int mt=0;mt<2;++mt)
      #pragma unroll
      for (int rg=0;rg<4;++rg) {
        const int row = mt*16 + lg*4 + rg;
        #pragma unroll
        for (int nt=0;nt<4;++nt) {
          const int col = nq*64 + nt*16 + lrow;
          ob[(size_t)row*H2 + col] = lrelu(acc2[mt][nt][rg] + bb2[nt]);
        }
      }
  }
}

extern "C" void kernel_launch(void* const* d_in, const int* in_sizes, int n_in,
                              void* d_out, int out_size, void* d_ws, size_t ws_size,
                              hipStream_t stream) {
  const float* xyz1    = (const float*)d_in[0];
  const float* xyz2    = (const float*)d_in[1];
  const float* points1 = (const float*)d_in[2];
  const float* points2 = (const float*)d_in[3];
  const float* W1      = (const float*)d_in[4];
  const float* b1      = (const float*)d_in[5];
  const float* W2      = (const float*)d_in[6];
  const float* b2      = (const float*)d_in[7];
  float* out = (float*)d_out;

  hipLaunchKernelGGL(k0_w, dim3(80), dim3(256), 0, stream, W1, W2, (char*)d_ws);
  hipLaunchKernelGGL(k1_nn_y2, dim3(1280), dim3(256), 0, stream,
                     xyz1, xyz2, points2, (char*)d_ws);
  hipLaunchKernelGGL(k2_mlp, dim3(NB * (N1 / TM)), dim3(256), 0, stream,
                     points1, (const char*)d_ws, b1, b2, out);
}

// Round 10
// 44.292 us; speedup vs baseline: 1.2708x; 1.2708x over previous
//
#include <hip/hip_runtime.h>

typedef __attribute__((ext_vector_type(8))) short bf16x8;
typedef __attribute__((ext_vector_type(4))) float f32x4;

namespace {
constexpr int NB=8, N1=4096, N2=1024, F1=128, F2=256, H2=256;
constexpr int TM=32;
constexpr float SLOPE=0.2f, EPSD=1e-10f;
constexpr size_t WS_W1=0;                     // 192 KB (12 steps * 16 frags * 1KB)
constexpr size_t WS_W2=196608;                // 128 KB
constexpr int XT_STRIDE=784;   // 768B row + 16B pad
constexpr int H_STRIDE=528;    // 512B row + 16B pad
}

__device__ __forceinline__ unsigned short f2bf(float f){
  union{float f; unsigned u;} v; v.f=f;
  unsigned r = v.u + 0x7FFFu + ((v.u>>16)&1u);   // RNE
  return (unsigned short)(r>>16);
}
__device__ __forceinline__ float lrelu(float x){ return x>=0.f? x : SLOPE*x; }

// ===== W1/W2 -> bf16 frag-linear: frag = s*16 + nq*4 + nt; lane ln holds 8
// k-bf16 for n = nq*64+nt*16+(ln&15), k0 = s*32+(ln>>4)*8 =====
__global__ __launch_bounds__(256)
void transform_w(const float* __restrict__ W1, const float* __restrict__ W2,
                 char* __restrict__ ws)
{
  int id = blockIdx.x*256 + threadIdx.x;
  const float* src; size_t dst;
  if (id < 12288) {                             // W1: 192 frags
    int frag = id >> 6, ln = id & 63;
    int n = (((frag>>2)&3)*64) + ((frag&3)*16) + (ln & 15);
    int k0 = (frag>>4)*32 + (ln>>4)*8;
    src = W1 + (size_t)k0*256 + n;
    dst = WS_W1 + (size_t)frag*1024 + ln*16;
  } else if (id < 20480) {                      // W2: 128 frags
    int fid = id - 12288, frag = fid >> 6, ln = fid & 63;
    int n = (((frag>>2)&3)*64) + ((frag&3)*16) + (ln & 15);
    int k0 = (frag>>4)*32 + (ln>>4)*8;
    src = W2 + (size_t)k0*256 + n;
    dst = WS_W2 + (size_t)frag*1024 + ln*16;
  } else return;
  unsigned u[4];
  #pragma unroll
  for (int p=0;p<4;++p)
    u[p] = (unsigned)f2bf(src[(2*p)*256]) | ((unsigned)f2bf(src[(2*p+1)*256])<<16);
  *(uint4*)(ws + dst) = make_uint4(u[0],u[1],u[2],u[3]);
}

// TM=32, 256 threads, grid 1024, no VGPR cap (rounds 4/6 lesson).
__global__ __launch_bounds__(256, 2)
void fp_mfma(const float* __restrict__ xyz1, const float* __restrict__ xyz2,
             const float* __restrict__ p1,   const float* __restrict__ p2,
             const char* __restrict__ ws,
             const float* __restrict__ b1,   const float* __restrict__ b2,
             float* __restrict__ out)
{
  __shared__ __align__(16) char smem[25088];   // A: xq 16K + cand 8K; B: Xt/h
  __shared__ float s_w[TM][4];
  __shared__ int   s_idx[TM][4];

  const int t = threadIdx.x;
  const int b = blockIdx.x & 7;                // batch == XCD
  const int row0 = (blockIdx.x >> 3) * TM;
  const int lane = t & 63, wv = t >> 6;
  const int lrow = lane & 15, lg = lane >> 4;
  const int nq = wv;

  // ===== Phase A: stage xyz2 -> LDS (x,y,z,sq), then 3-NN scan from LDS =====
  {
    float4* xq = (float4*)smem;                // [0, 16384)
    char* cand = smem + 16384;                 // [16384, 24576)
    const float* xz = xyz2 + (size_t)b*N2*3;
    for (int j = t; j < N2; j += 256) {
      float x = xz[3*j], y = xz[3*j+1], z = xz[3*j+2];
      xq[j] = make_float4(x, y, z, x*x + y*y + z*z);
    }
    __syncthreads();
    {
      const int row = lane & 31, slice = wv*2 + (lane >> 5);  // LDS broadcast reads
      const float* x1 = xyz1 + ((size_t)b*N1 + row0 + row)*3;
      const float px=x1[0], py=x1[1], pz=x1[2];
      const float sq1 = px*px + py*py + pz*pz;
      float d0=3.4e38f, d1=3.4e38f, d2=3.4e38f;
      int i0=0, i1=0, i2=0;
      const int j0 = slice*128;
      #pragma unroll 8
      for (int j = j0; j < j0+128; ++j) {
        float4 q = xq[j];
        float dot = px*q.x + py*q.y + pz*q.z;
        float d = fmaf(-2.f, dot, sq1 + q.w);
        bool c0 = d < d0, c1 = d < d1, c2 = d < d2;
        i2 = c1 ? i1 : (c2 ? j : i2);
        i1 = c0 ? i0 : (c1 ? j : i1);
        i0 = c0 ? j  : i0;
        d2 = __builtin_amdgcn_fmed3f(d, d1, d2);
        d1 = __builtin_amdgcn_fmed3f(d, d0, d1);
        d0 = fminf(d, d0);
      }
      float* cd = (float*)(cand + (slice*32 + row)*32);
      cd[0]=d0; cd[1]=d1; cd[2]=d2;
      ((int*)cd)[4]=i0; ((int*)cd)[5]=i1; ((int*)cd)[6]=i2;
    }
    __syncthreads();
    if (t < TM) {                              // merge 8 slices, j-ascending
      const char* cand_ = smem + 16384;
      float d0=3.4e38f,d1=3.4e38f,d2=3.4e38f; int i0=0,i1=0,i2=0;
      for (int p=0;p<8;++p){
        const float* cd = (const float*)(cand_ + (p*32 + t)*32);
        for (int c=0;c<3;++c){
          float d = cd[c]; int ii = ((const int*)cd)[4+c];
          if (d < d2) {
            if (d < d1) { d2=d1; i2=i1;
              if (d < d0) { d1=d0; i1=i0; d0=d; i0=ii; } else { d1=d; i1=ii; }
            } else { d2=d; i2=ii; }
          }
        }
      }
      d0=fmaxf(d0,EPSD); d1=fmaxf(d1,EPSD); d2=fmaxf(d2,EPSD);
      float w0=1.f/d0, w1=1.f/d1, w2=1.f/d2, inv=1.f/(w0+w1+w2);
      s_w[t][0]=w0*inv; s_w[t][1]=w1*inv; s_w[t][2]=w2*inv;
      s_idx[t][0]=i0; s_idx[t][1]=i1; s_idx[t][2]=i2;
    }
    __syncthreads();
  }

  // ===== Phase B =====
  const int rr = t >> 3, qq = t & 7;           // X build: 8 thr/row, 8 k each
  const float w0_=s_w[rr][0], w1_=s_w[rr][1], w2_=s_w[rr][2];
  const int g0=s_idx[rr][0], g1=s_idx[rr][1], g2=s_idx[rr][2];
  const char* wsW1 = ws + WS_W1;
  const char* wsW2 = ws + WS_W2;
  const float* p2b = p2 + (size_t)b*N2*F2;
  const float* p1r = p1 + ((size_t)b*N1 + row0 + rr)*F1;

  auto issueAny = [&](int kcg, float4* g){
    if (kcg < 4) {
      const int k0 = kcg*64 + qq*8;
      const float4* q0 = (const float4*)(p2b + (size_t)g0*F2 + k0);
      const float4* q1 = (const float4*)(p2b + (size_t)g1*F2 + k0);
      const float4* q2 = (const float4*)(p2b + (size_t)g2*F2 + k0);
      g[0]=q0[0]; g[1]=q0[1]; g[2]=q1[0]; g[3]=q1[1]; g[4]=q2[0]; g[5]=q2[1];
    } else {
      const float4* q = (const float4*)(p1r + (kcg*64 + qq*8 - F2));
      g[0]=q[0]; g[1]=q[1];
    }
  };
  auto writeAny = [&](int kcg, const float4* g){
    float v[8];
    if (kcg < 4) {
      #pragma unroll
      for (int p=0;p<2;++p){
        v[4*p+0] = fmaf(w2_, g[4+p].x, fmaf(w1_, g[2+p].x, w0_*g[p].x));
        v[4*p+1] = fmaf(w2_, g[4+p].y, fmaf(w1_, g[2+p].y, w0_*g[p].y));
        v[4*p+2] = fmaf(w2_, g[4+p].z, fmaf(w1_, g[2+p].z, w0_*g[p].z));
        v[4*p+3] = fmaf(w2_, g[4+p].w, fmaf(w1_, g[2+p].w, w0_*g[p].w));
      }
    } else {
      #pragma unroll
      for (int p=0;p<2;++p){
        v[4*p+0]=g[p].x; v[4*p+1]=g[p].y; v[4*p+2]=g[p].z; v[4*p+3]=g[p].w;
      }
    }
    unsigned u[4];
    #pragma unroll
    for (int p=0;p<4;++p)
      u[p] = (unsigned)f2bf(v[2*p]) | ((unsigned)f2bf(v[2*p+1])<<16);
    *(uint4*)(smem + rr*XT_STRIDE + (kcg*8 + qq)*16) = make_uint4(u[0],u[1],u[2],u[3]);
  };
  auto loadW = [&](const char* base, int s, bf16x8* dst){
    #pragma unroll
    for (int nt=0;nt<4;++nt)
      dst[nt] = *(const bf16x8*)(base + ((s*16 + nq*4 + nt)<<10) + lane*16);
  };
  auto gemmStep = [&](int s, const bf16x8* bw, f32x4 (&ac)[2][4],
                      const char* Ab, int stride){
    bf16x8 af[2];
    #pragma unroll
    for (int mt=0;mt<2;++mt)
      af[mt] = *(const bf16x8*)(Ab + (mt*16+lrow)*stride + (s*4+lg)*16);
    #pragma unroll
    for (int mt=0;mt<2;++mt)
      #pragma unroll
      for (int nt=0;nt<4;++nt)
        ac[mt][nt] = __builtin_amdgcn_mfma_f32_16x16x32_bf16(af[mt], bw[nt], ac[mt][nt], 0,0,0);
  };

  f32x4 acc[2][4];
  #pragma unroll
  for (int mt=0;mt<2;++mt)
    #pragma unroll
    for (int nt=0;nt<4;++nt) acc[mt][nt] = (f32x4){0.f,0.f,0.f,0.f};

  // ---- W steps 0..2 prefetch FIRST (L2 latency hides under X build) ----
  bf16x8 bwA[4], bwB[4], bwC[4];
  loadW(wsW1, 0, bwA);
  loadW(wsW1, 1, bwB);
  loadW(wsW1, 2, bwC);

  // ---- build full X tile (32 x 384), depth-2 gather pipeline ----
  float4 ga[6], gb[6];
  issueAny(0, ga); issueAny(1, gb);
  writeAny(0, ga); issueAny(2, ga);
  writeAny(1, gb); issueAny(3, gb);
  writeAny(2, ga); issueAny(4, ga);
  writeAny(3, gb); issueAny(5, gb);
  writeAny(4, ga); writeAny(5, gb);
  __syncthreads();

  // ---- GEMM1: 12 K32 steps, no internal barriers, W prefetch distance 3 ----
  #pragma unroll
  for (int u=0; u<4; ++u) {
    gemmStep(3*u,   bwA, acc, smem, XT_STRIDE);
    if (u<3) loadW(wsW1, 3*u+3, bwA); else loadW(wsW2, 0, bwA);
    gemmStep(3*u+1, bwB, acc, smem, XT_STRIDE);
    if (u<3) loadW(wsW1, 3*u+4, bwB); else loadW(wsW2, 1, bwB);
    gemmStep(3*u+2, bwC, acc, smem, XT_STRIDE);
    if (u<3) loadW(wsW1, 3*u+5, bwC); else loadW(wsW2, 2, bwC);
  }
  __syncthreads();                             // Xt dead

  // ---- h = lrelu(acc + b1) -> LDS [32][264 shorts] ----
  {
    float bb[4];
    #pragma unroll
    for (int nt=0;nt<4;++nt) bb[nt] = b1[nq*64 + nt*16 + lrow];
    #pragma unroll
    for (int mt=0;mt<2;++mt)
      #pragma unroll
      for (int rg=0;rg<4;++rg) {
        const int row = mt*16 + lg*4 + rg;
        #pragma unroll
        for (int nt=0;nt<4;++nt) {
          const int col = nq*64 + nt*16 + lrow;
          *(short*)(smem + row*H_STRIDE + col*2) =
              (short)f2bf(lrelu(acc[mt][nt][rg] + bb[nt]));
        }
      }
  }
  __syncthreads();

  // ---- GEMM2: h(32x256) @ W2, 8 K32 steps, dist-3 rotation ----
  f32x4 acc2[2][4];
  #pragma unroll
  for (int mt=0;mt<2;++mt)
    #pragma unroll
    for (int nt=0;nt<4;++nt) acc2[mt][nt] = (f32x4){0.f,0.f,0.f,0.f};
  gemmStep(0, bwA, acc2, smem, H_STRIDE); loadW(wsW2, 3, bwA);
  gemmStep(1, bwB, acc2, smem, H_STRIDE); loadW(wsW2, 4, bwB);
  gemmStep(2, bwC, acc2, smem, H_STRIDE); loadW(wsW2, 5, bwC);
  gemmStep(3, bwA, acc2, smem, H_STRIDE); loadW(wsW2, 6, bwA);
  gemmStep(4, bwB, acc2, smem, H_STRIDE); loadW(wsW2, 7, bwB);
  gemmStep(5, bwC, acc2, smem, H_STRIDE);
  gemmStep(6, bwA, acc2, smem, H_STRIDE);
  gemmStep(7, bwB, acc2, smem, H_STRIDE);

  // ---- epilogue ----
  {
    float bb[4];
    #pragma unroll
    for (int nt=0;nt<4;++nt) bb[nt] = b2[nq*64 + nt*16 + lrow];
    float* ob = out + ((size_t)b*N1 + row0) * H2;
    #pragma unroll
    for (int mt=0;mt<2;++mt)
      #pragma unroll
      for (int rg=0;rg<4;++rg) {
        const int row = mt*16 + lg*4 + rg;
        #pragma unroll
        for (int nt=0;nt<4;++nt) {
          const int col = nq*64 + nt*16 + lrow;
          ob[(size_t)row*H2 + col] = lrelu(acc2[mt][nt][rg] + bb[nt]);
        }
      }
  }
}

extern "C" void kernel_launch(void* const* d_in, const int* in_sizes, int n_in,
                              void* d_out, int out_size, void* d_ws, size_t ws_size,
                              hipStream_t stream) {
  const float* xyz1    = (const float*)d_in[0];
  const float* xyz2    = (const float*)d_in[1];
  const float* points1 = (const float*)d_in[2];
  const float* points2 = (const float*)d_in[3];
  const float* W1      = (const float*)d_in[4];
  const float* b1      = (const float*)d_in[5];
  const float* W2      = (const float*)d_in[6];
  const float* b2      = (const float*)d_in[7];
  float* out = (float*)d_out;

  hipLaunchKernelGGL(transform_w, dim3(80), dim3(256), 0, stream, W1, W2, (char*)d_ws);
  hipLaunchKernelGGL(fp_mfma, dim3(NB * (N1 / TM)), dim3(256), 0, stream,
                     xyz1, xyz2, points1, points2, (const char*)d_ws, b1, b2, out);
}